// Round 2
// baseline (916.778 us; speedup 1.0000x reference)
//
#include <hip/hip_runtime.h>
#include <hip/hip_bf16.h>

#define B_ROWS 1024
#define F_FLD  160000
#define D_DIM  16
#define NKB    (F_FLD / 32)        // 5000 K-blocks of 32 cols
#define NSTAT  (D_DIM + 1)         // 16 ev + cacc
#define ACC_N  (B_ROWS * NSTAT)    // 17408
#define CCOLS  6400                // cols per block chunk
#define NGRP   (CCOLS / 256)       // 25 ballot groups per chunk
#define NGRP_T (F_FLD / 256)       // 625 ballot groups per row total
#define KBC    (CCOLS / 32)        // 200 K-blocks per chunk
#define NCHUNK (F_FLD / CCOLS)     // 25
#define ROWS_B 32                  // rows per block
#define ROWBLK (B_ROWS / ROWS_B)   // 32 row-blocks
#define WAVES  8                   // 512 threads
#define PREBLK 256                 // pre-pass blocks (4 row-waves each -> 1024 rows)
#define PACKBLK (NKB / 4)          // 1250 pack blocks

typedef __attribute__((ext_vector_type(8))) short bf16x8;
typedef __attribute__((ext_vector_type(4))) float f32x4;

static __device__ inline unsigned short f2bf(float x) {
    __hip_bfloat16 h = __float2bfloat16(x);
    union { __hip_bfloat16 h; unsigned short s; } u; u.h = h; return u.s;
}

// Expand 8 mask bits -> 8 bf16 (1.0/0.0) in A-fragment register order.
// (verbatim from R4/R5, passing with absmax = bf16 noise)
static __device__ inline bf16x8 expand8(unsigned b) {
    union { unsigned u[4]; bf16x8 v; } r;
    r.u[0] = ((b        & 1u) * 0x3F80u) | (((b >> 1) & 1u) * 0x3F800000u);
    r.u[1] = (((b >> 2) & 1u) * 0x3F80u) | (((b >> 3) & 1u) * 0x3F800000u);
    r.u[2] = (((b >> 4) & 1u) * 0x3F80u) | (((b >> 5) & 1u) * 0x3F800000u);
    r.u[3] = (((b >> 6) & 1u) * 0x3F80u) | (((b >> 7) & 1u) * 0x3F800000u);
    return r.v;
}

// R7: fused prep = { x -> bitmask pre-pass } + { emb/bias -> MFMA-fragment pack }.
// Pre-pass: 1024 waves (1 per SIMD), each streams ONE x row (640 KB sequential)
// with 2-deep-pipelined 5x1KB batches (10 loads in flight), ballots -> 32 B of
// mask per 1 KB of x. Pure stream: no barrier, no LDS, no phase lockstep.
// bm[row][gg][q]: bit l of word q at group gg  <->  col gg*256 + 4l + q.
// Pack blocks (grid tail) hide their ~15 us of VALU under the pre-pass stream.
__global__ __launch_bounds__(256) void fm_prep(const int* __restrict__ x,
                                               const float* __restrict__ emb,
                                               const float* __restrict__ bias,
                                               unsigned long long* __restrict__ bm,
                                               unsigned short* __restrict__ embB,
                                               unsigned short* __restrict__ cB2c,
                                               float* __restrict__ acc) {
    const int tid = threadIdx.x;
    if (blockIdx.x < PREBLK) {
        // ---- x -> bitmask stream
        const int w = tid >> 6, l = tid & 63;
        const int row = blockIdx.x * 4 + w;
        const int4* xp = (const int4*)(x + (size_t)row * F_FLD) + l;
        unsigned long long* dst = bm + (size_t)row * NGRP_T * 4;

        int4 va[5], vb[5];
#pragma unroll
        for (int k = 0; k < 5; ++k) va[k] = xp[(size_t)k * 64];
        for (int g0 = 0; g0 < NGRP_T; g0 += 5) {
            const int nx = g0 + 5;
            if (nx < NGRP_T) {
#pragma unroll
                for (int k = 0; k < 5; ++k) vb[k] = xp[(size_t)(nx + k) * 64];
            }
#pragma unroll
            for (int k = 0; k < 5; ++k) {
                unsigned long long m0 = __ballot(va[k].x > 0);
                unsigned long long m1 = __ballot(va[k].y > 0);
                unsigned long long m2 = __ballot(va[k].z > 0);
                unsigned long long m3 = __ballot(va[k].w > 0);
                unsigned long long mv = (l == 1) ? m1 : (l == 2) ? m2 : (l == 3) ? m3 : m0;
                if (l < 4) dst[(size_t)(g0 + k) * 4 + l] = mv;
            }
            if (nx < NGRP_T) {
#pragma unroll
                for (int k = 0; k < 5; ++k) va[k] = vb[k];
            }
        }
    } else {
        // ---- pack emb -> B-frag bf16 + c -> broadcast-B (verbatim R5/R6 fm_pack)
        const int bid = blockIdx.x - PREBLK;
        const int kb = bid * 4 + (tid >> 6);
        const int l = tid & 63, q = l >> 4, n = l & 15;

        float e[8];
        union { unsigned short s[8]; uint4 u; } v;
#pragma unroll
        for (int j = 0; j < 8; ++j) {
            int f = kb * 32 + 4 * j + q;
            e[j] = emb[(size_t)f * D_DIM + n];
            v.s[j] = f2bf(e[j]);
        }
        *(uint4*)(embB + ((size_t)kb * 64 + l) * 8) = v.u;

        union { unsigned short s[8]; uint4 u; } wv;
#pragma unroll
        for (int j = 0; j < 8; ++j) {
            float s = e[j] * e[j];                    // reduce over n (16 lanes)
            s += __shfl_xor(s, 1);
            s += __shfl_xor(s, 2);
            s += __shfl_xor(s, 4);
            s += __shfl_xor(s, 8);
            int f = kb * 32 + 4 * j + q;
            wv.s[j] = f2bf((n == 0 ? bias[f] : 0.0f) - 0.5f * s);
        }
        if (n == 0) *(uint4*)(cB2c + ((size_t)kb * 4 + q) * 8) = wv.u;

        int gid = bid * 256 + tid;
        if (gid < ACC_N) acc[gid] = 0.0f;              // ws poisoned every call
    }
}

// Main: now compute-only. Stage = 25.6 KB of precomputed masks per block
// (one uint4 per <50 lanes per row) instead of 819 KB of raw x. Compute path
// (expand8 / fragment mappings / MFMAs / reduce) byte-identical to R6; msk
// indexing transposed to [row][g][q] to match bm's row-major layout.
__global__ __launch_bounds__(512, 6) void fm_main(const unsigned long long* __restrict__ bm,
                                                  const unsigned short* __restrict__ embB,
                                                  const unsigned short* __restrict__ cB2c,
                                                  float* __restrict__ acc) {
    __shared__ unsigned long long msk[ROWS_B][NGRP][4];   // 25.6 KB
    __shared__ float red[WAVES][ROWS_B][NSTAT];           // 17.4 KB

    const int tid = threadIdx.x;
    const int w = tid >> 6, l = tid & 63;
    const int q = l >> 4, n = l & 15;
    const int rowbase = blockIdx.x * ROWS_B;   // rowblock = fastest grid dim
    const int ch = blockIdx.y;                 // chunk    = slow grid dim

    // ---- stage: wave w -> rows 4w..4w+3; 800 B of masks per row, 50 lanes x 16 B
#pragma unroll
    for (int rr = 0; rr < 4; ++rr) {
        const int rloc = 4 * w + rr;
        const uint4* src = (const uint4*)(bm + ((size_t)(rowbase + rloc) * NGRP_T
                                                + (size_t)ch * NGRP) * 4);
        if (l < NGRP * 2) {
            ((uint4*)&msk[rloc][0][0])[l] = src[l];
        }
    }
    __syncthreads();

    // ---- compute: wave w owns K-blocks w*25 .. w*25+24; one eB load feeds
    // both row-halves (rows 0-15 via A0, rows 16-31 via A1).
    f32x4 aev0 = {0.f, 0.f, 0.f, 0.f}, ac0 = {0.f, 0.f, 0.f, 0.f};
    f32x4 aev1 = {0.f, 0.f, 0.f, 0.f}, ac1 = {0.f, 0.f, 0.f, 0.f};
    const uint4* eB = (const uint4*)embB;
    const uint4* cB = (const uint4*)cB2c;
    const int kbg0 = blockIdx.y * KBC;

#pragma unroll 2
    for (int t = 0; t < KBC / WAVES; ++t) {
        const int kb = w * (KBC / WAVES) + t;        // 0..199 within chunk
        const int g = kb >> 3, byt = kb & 7;
        // A byte: bits j of byte `byt` of word q, row n  (verified mapping:
        // col kb*32 + 4j + q  ==  bit (byt*8+j) of word q at group g)
        unsigned long long mv0 = msk[n][g][q];
        unsigned long long mv1 = msk[n + 16][g][q];
        unsigned b0 = (unsigned)(mv0 >> (8 * byt)) & 0xFFu;
        unsigned b1 = (unsigned)(mv1 >> (8 * byt)) & 0xFFu;
        bf16x8 A0 = expand8(b0);
        bf16x8 A1 = expand8(b1);
        union { uint4 u; bf16x8 v; } Bf, Cf;
        Bf.u = eB[(size_t)(kbg0 + kb) * 64 + l];
        Cf.u = cB[(size_t)(kbg0 + kb) * 4 + q];
        aev0 = __builtin_amdgcn_mfma_f32_16x16x32_bf16(A0, Bf.v, aev0, 0, 0, 0);
        ac0  = __builtin_amdgcn_mfma_f32_16x16x32_bf16(A0, Cf.v, ac0,  0, 0, 0);
        aev1 = __builtin_amdgcn_mfma_f32_16x16x32_bf16(A1, Bf.v, aev1, 0, 0, 0);
        ac1  = __builtin_amdgcn_mfma_f32_16x16x32_bf16(A1, Cf.v, ac1,  0, 0, 0);
    }

    // ---- reduce 8 wave-partials (C/D layout: row = q*4+r, col = n;
    // A1's outputs land on block rows 16 + q*4+r)
#pragma unroll
    for (int r = 0; r < 4; ++r) {
        red[w][q * 4 + r][n] = aev0[r];
        red[w][16 + q * 4 + r][n] = aev1[r];
        if (n == 0) {
            red[w][q * 4 + r][16] = ac0[r];
            red[w][16 + q * 4 + r][16] = ac1[r];
        }
    }
    __syncthreads();

    for (int i = tid; i < ROWS_B * NSTAT; i += 512) {
        int row = i / NSTAT, col = i % NSTAT;
        float s = 0.0f;
#pragma unroll
        for (int ww = 0; ww < WAVES; ++ww) s += red[ww][row][col];
        atomicAdd(acc + (size_t)(rowbase + row) * NSTAT + col, s);
    }
}

// out[b] = g_bias + cacc[b] + 0.5 * ||ev[b]||^2
__global__ __launch_bounds__(256) void fm_final(const float* __restrict__ acc,
                                                const float* __restrict__ g_bias,
                                                float* __restrict__ out) {
    int row = blockIdx.x * 256 + threadIdx.x;
    if (row >= B_ROWS) return;
    const float* a = acc + (size_t)row * NSTAT;
    float s = 0.0f;
#pragma unroll
    for (int d = 0; d < D_DIM; ++d) s += a[d] * a[d];
    out[row] = g_bias[0] + a[16] + 0.5f * s;
}

extern "C" void kernel_launch(void* const* d_in, const int* in_sizes, int n_in,
                              void* d_out, int out_size, void* d_ws, size_t ws_size,
                              hipStream_t stream) {
    const int*   x      = (const int*)d_in[0];
    const float* emb_w  = (const float*)d_in[1];
    const float* bias_w = (const float*)d_in[2];
    const float* g_bias = (const float*)d_in[3];
    float*       out    = (float*)d_out;

    // ws: embB 5,120,000 | cB2c 320,000 | acc 69,632 | bm 20,480,000
    unsigned short* embB = (unsigned short*)d_ws;
    unsigned short* cB2c = (unsigned short*)((char*)d_ws + (size_t)NKB * 64 * 8 * 2);
    float*          acc  = (float*)((char*)d_ws + (size_t)NKB * 64 * 8 * 2
                                                + (size_t)NKB * 4 * 8 * 2);
    unsigned long long* bm = (unsigned long long*)((char*)d_ws
                                                + (size_t)NKB * 64 * 8 * 2
                                                + (size_t)NKB * 4 * 8 * 2
                                                + (size_t)ACC_N * 4);

    fm_prep<<<dim3(PREBLK + PACKBLK), dim3(256), 0, stream>>>(x, emb_w, bias_w,
                                                              bm, embB, cB2c, acc);
    fm_main<<<dim3(ROWBLK, NCHUNK), dim3(512), 0, stream>>>(bm, embB, cB2c, acc);
    fm_final<<<dim3((B_ROWS + 255) / 256), dim3(256), 0, stream>>>(acc, g_bias, out);
}

// Round 3
// 895.788 us; speedup vs baseline: 1.0234x; 1.0234x over previous
//
#include <hip/hip_runtime.h>
#include <hip/hip_bf16.h>

#define B_ROWS 1024
#define F_FLD  160000
#define D_DIM  16
#define NKB    (F_FLD / 32)        // 5000 K-blocks of 32 cols
#define NSTAT  (D_DIM + 1)         // 16 ev + cacc
#define ACC_N  (B_ROWS * NSTAT)    // 17408
#define SEGC   1280                // cols per segment (= 5 ballot groups)
#define NSEG   (F_FLD / SEGC)      // 125 segments per row
#define CCOLS  6400                // cols per block chunk
#define NGRP   (CCOLS / 256)       // 25 ballot groups per chunk
#define SEGB   (CCOLS / SEGC)      // 5 segments per chunk
#define KBC    (CCOLS / 32)        // 200 K-blocks per chunk
#define NCHUNK (F_FLD / CCOLS)     // 25
#define ROWS_B 32                  // rows per block
#define ROWBLK (B_ROWS / ROWS_B)   // 32 row-blocks
#define WAVES  8                   // 512 threads
#define SBLK   2000                // stream blocks (8/CU -> full occupancy)
#define SWAVES (SBLK * 4)          // 8000 stream waves
#define UNITS  (B_ROWS * NSEG)     // 128000 row-segments
#define UPW    (UNITS / SWAVES)    // 16 units per wave
#define PACKBLK (NKB / 4)          // 1250 pack blocks

typedef __attribute__((ext_vector_type(8))) short bf16x8;
typedef __attribute__((ext_vector_type(4))) float f32x4;

static __device__ inline unsigned short f2bf(float x) {
    __hip_bfloat16 h = __float2bfloat16(x);
    union { __hip_bfloat16 h; unsigned short s; } u; u.h = h; return u.s;
}

// Expand 8 mask bits -> 8 bf16 (1.0/0.0) in A-fragment register order.
// (verbatim from R4/R5, passing with absmax = bf16 noise)
static __device__ inline bf16x8 expand8(unsigned b) {
    union { unsigned u[4]; bf16x8 v; } r;
    r.u[0] = ((b        & 1u) * 0x3F80u) | (((b >> 1) & 1u) * 0x3F800000u);
    r.u[1] = (((b >> 2) & 1u) * 0x3F80u) | (((b >> 3) & 1u) * 0x3F800000u);
    r.u[2] = (((b >> 4) & 1u) * 0x3F80u) | (((b >> 5) & 1u) * 0x3F800000u);
    r.u[3] = (((b >> 6) & 1u) * 0x3F80u) | (((b >> 7) & 1u) * 0x3F800000u);
    return r.v;
}

// R8: copy-shaped x reader. NO cross-lane ops in the stream: per unit
// (row-segment, 1280 cols = 5 KB) each lane packs its 20 values into one
// dword (bit 4k+r of lane l <-> col seg*1280 + k*256 + 4l + r), coalesced
// dword store. Interleaved grid-stride (u = i*SWAVES + gw) makes the
// instantaneous footprint a contiguous window sweeping x, like fill/copy.
// Even/odd ping-pong keeps >=5 loads in flight at all times (no vmcnt(0)
// drains - the R6/R7 readers drained every batch and capped at ~3 TB/s).
__global__ __launch_bounds__(256) void fm_prep(const int* __restrict__ x,
                                               const float* __restrict__ emb,
                                               const float* __restrict__ bias,
                                               unsigned* __restrict__ bm2,
                                               unsigned short* __restrict__ embB,
                                               unsigned short* __restrict__ cB2c,
                                               float* __restrict__ acc) {
    const int tid = threadIdx.x;
    if (blockIdx.x < SBLK) {
        const int gw = blockIdx.x * 4 + (tid >> 6);
        const int l = tid & 63;
        const int4* xb = (const int4*)x;   // unit u = row*NSEG+seg -> x int4 base u*320 (linear!)

        int4 a[5], b[5];
        auto LD = [&](int4 (&r)[5], int u) {
            const int4* p = xb + (size_t)u * (SEGC / 4) + l;
#pragma unroll
            for (int k = 0; k < 5; ++k) r[k] = p[(size_t)k * 64];
        };
        auto ST = [&](int4 (&r)[5], int u) {
            unsigned m = 0;
#pragma unroll
            for (int k = 0; k < 5; ++k) {
                unsigned nib = (unsigned)(r[k].x > 0) | ((unsigned)(r[k].y > 0) << 1)
                             | ((unsigned)(r[k].z > 0) << 2) | ((unsigned)(r[k].w > 0) << 3);
                m |= nib << (4 * k);
            }
            bm2[(size_t)u * 64 + l] = m;
        };

        LD(a, gw);
#pragma unroll 1
        for (int i = 0; i < UPW; i += 2) {
            LD(b, gw + (i + 1) * SWAVES);
            ST(a, gw + i * SWAVES);
            if (i + 2 < UPW) LD(a, gw + (i + 2) * SWAVES);
            ST(b, gw + (i + 1) * SWAVES);
        }
    } else {
        // ---- pack emb -> B-frag bf16 + c -> broadcast-B (verbatim R5-R7)
        const int bid = blockIdx.x - SBLK;
        const int kb = bid * 4 + (tid >> 6);
        const int l = tid & 63, q = l >> 4, n = l & 15;

        float e[8];
        union { unsigned short s[8]; uint4 u; } v;
#pragma unroll
        for (int j = 0; j < 8; ++j) {
            int f = kb * 32 + 4 * j + q;
            e[j] = emb[(size_t)f * D_DIM + n];
            v.s[j] = f2bf(e[j]);
        }
        *(uint4*)(embB + ((size_t)kb * 64 + l) * 8) = v.u;

        union { unsigned short s[8]; uint4 u; } wv;
#pragma unroll
        for (int j = 0; j < 8; ++j) {
            float s = e[j] * e[j];                    // reduce over n (16 lanes)
            s += __shfl_xor(s, 1);
            s += __shfl_xor(s, 2);
            s += __shfl_xor(s, 4);
            s += __shfl_xor(s, 8);
            int f = kb * 32 + 4 * j + q;
            wv.s[j] = f2bf((n == 0 ? bias[f] : 0.0f) - 0.5f * s);
        }
        if (n == 0) *(uint4*)(cB2c + ((size_t)kb * 4 + q) * 8) = wv.u;

        int gid = bid * 256 + tid;
        if (gid < ACC_N) acc[gid] = 0.0f;              // ws poisoned every call
    }
}

// Main: stage = 40 KB of packed bm2 per block (vs 819 KB of raw x), then
// reconstruct the verified ballot-mask layout IN LDS via register-sourced
// ballots: bit (4j+q) of lane l's word <-> col seg*1280+j*256+4l+q, so
// __ballot((m>>(4j+q))&1) yields exactly "bit l of word q at group g <->
// col g*256+4l+q" (the R5/R6 convention). Compute path byte-identical to R6.
__global__ __launch_bounds__(512, 6) void fm_main(const unsigned* __restrict__ bm2,
                                                  const unsigned short* __restrict__ embB,
                                                  const unsigned short* __restrict__ cB2c,
                                                  float* __restrict__ acc) {
    __shared__ unsigned long long msk[NGRP][ROWS_B][4];   // 25.6 KB
    __shared__ float red[WAVES][ROWS_B][NSTAT];           // 17.4 KB

    const int tid = threadIdx.x;
    const int w = tid >> 6, l = tid & 63;
    const int q = l >> 4, n = l & 15;
    const int rowbase = blockIdx.x * ROWS_B;   // rowblock = fastest grid dim
    const int ch = blockIdx.y;                 // chunk    = slow grid dim

    // ---- stage: wave w -> rows 4w..4w+3; 5 dword loads per row, then
    // 100 ballots per row rebuild msk (all indices compile-time static)
#pragma unroll
    for (int rr = 0; rr < 4; ++rr) {
        const int rloc = 4 * w + rr;
        const unsigned* src = bm2 + ((size_t)(rowbase + rloc) * NSEG
                                     + (size_t)ch * SEGB) * 64 + l;
        unsigned mreg[SEGB];
#pragma unroll
        for (int s = 0; s < SEGB; ++s) mreg[s] = src[(size_t)s * 64];
#pragma unroll
        for (int s = 0; s < SEGB; ++s) {
            const unsigned m = mreg[s];
#pragma unroll
            for (int j = 0; j < 5; ++j) {
                const int g = s * 5 + j;
                unsigned long long b0 = __ballot((m >> (4 * j + 0)) & 1u);
                unsigned long long b1 = __ballot((m >> (4 * j + 1)) & 1u);
                unsigned long long b2 = __ballot((m >> (4 * j + 2)) & 1u);
                unsigned long long b3 = __ballot((m >> (4 * j + 3)) & 1u);
                if (l == 0) {
                    msk[g][rloc][0] = b0; msk[g][rloc][1] = b1;
                    msk[g][rloc][2] = b2; msk[g][rloc][3] = b3;
                }
            }
        }
    }
    __syncthreads();

    // ---- compute: wave w owns K-blocks w*25 .. w*25+24; one eB load feeds
    // both row-halves (rows 0-15 via A0, rows 16-31 via A1). Verbatim R6.
    f32x4 aev0 = {0.f, 0.f, 0.f, 0.f}, ac0 = {0.f, 0.f, 0.f, 0.f};
    f32x4 aev1 = {0.f, 0.f, 0.f, 0.f}, ac1 = {0.f, 0.f, 0.f, 0.f};
    const uint4* eB = (const uint4*)embB;
    const uint4* cB = (const uint4*)cB2c;
    const int kbg0 = blockIdx.y * KBC;

#pragma unroll 2
    for (int t = 0; t < KBC / WAVES; ++t) {
        const int kb = w * (KBC / WAVES) + t;        // 0..199 within chunk
        const int g = kb >> 3, byt = kb & 7;
        // A byte: bits j of byte `byt` of word q, row n  (verified mapping:
        // col kb*32 + 4j + q  ==  bit (byt*8+j) of word q at group g)
        unsigned long long mv0 = msk[g][n][q];
        unsigned long long mv1 = msk[g][n + 16][q];
        unsigned b0 = (unsigned)(mv0 >> (8 * byt)) & 0xFFu;
        unsigned b1 = (unsigned)(mv1 >> (8 * byt)) & 0xFFu;
        bf16x8 A0 = expand8(b0);
        bf16x8 A1 = expand8(b1);
        union { uint4 u; bf16x8 v; } Bf, Cf;
        Bf.u = eB[(size_t)(kbg0 + kb) * 64 + l];
        Cf.u = cB[(size_t)(kbg0 + kb) * 4 + q];
        aev0 = __builtin_amdgcn_mfma_f32_16x16x32_bf16(A0, Bf.v, aev0, 0, 0, 0);
        ac0  = __builtin_amdgcn_mfma_f32_16x16x32_bf16(A0, Cf.v, ac0,  0, 0, 0);
        aev1 = __builtin_amdgcn_mfma_f32_16x16x32_bf16(A1, Bf.v, aev1, 0, 0, 0);
        ac1  = __builtin_amdgcn_mfma_f32_16x16x32_bf16(A1, Cf.v, ac1,  0, 0, 0);
    }

    // ---- reduce 8 wave-partials (C/D layout: row = q*4+r, col = n;
    // A1's outputs land on block rows 16 + q*4+r)
#pragma unroll
    for (int r = 0; r < 4; ++r) {
        red[w][q * 4 + r][n] = aev0[r];
        red[w][16 + q * 4 + r][n] = aev1[r];
        if (n == 0) {
            red[w][q * 4 + r][16] = ac0[r];
            red[w][16 + q * 4 + r][16] = ac1[r];
        }
    }
    __syncthreads();

    for (int i = tid; i < ROWS_B * NSTAT; i += 512) {
        int row = i / NSTAT, col = i % NSTAT;
        float s = 0.0f;
#pragma unroll
        for (int ww = 0; ww < WAVES; ++ww) s += red[ww][row][col];
        atomicAdd(acc + (size_t)(rowbase + row) * NSTAT + col, s);
    }
}

// out[b] = g_bias + cacc[b] + 0.5 * ||ev[b]||^2
__global__ __launch_bounds__(256) void fm_final(const float* __restrict__ acc,
                                                const float* __restrict__ g_bias,
                                                float* __restrict__ out) {
    int row = blockIdx.x * 256 + threadIdx.x;
    if (row >= B_ROWS) return;
    const float* a = acc + (size_t)row * NSTAT;
    float s = 0.0f;
#pragma unroll
    for (int d = 0; d < D_DIM; ++d) s += a[d] * a[d];
    out[row] = g_bias[0] + a[16] + 0.5f * s;
}

extern "C" void kernel_launch(void* const* d_in, const int* in_sizes, int n_in,
                              void* d_out, int out_size, void* d_ws, size_t ws_size,
                              hipStream_t stream) {
    const int*   x      = (const int*)d_in[0];
    const float* emb_w  = (const float*)d_in[1];
    const float* bias_w = (const float*)d_in[2];
    const float* g_bias = (const float*)d_in[3];
    float*       out    = (float*)d_out;

    // ws: embB 5,120,000 | cB2c 320,000 | acc 69,632 | bm2 32,768,000
    unsigned short* embB = (unsigned short*)d_ws;
    unsigned short* cB2c = (unsigned short*)((char*)d_ws + (size_t)NKB * 64 * 8 * 2);
    float*          acc  = (float*)((char*)d_ws + (size_t)NKB * 64 * 8 * 2
                                                + (size_t)NKB * 4 * 8 * 2);
    unsigned*       bm2  = (unsigned*)((char*)d_ws + (size_t)NKB * 64 * 8 * 2
                                                   + (size_t)NKB * 4 * 8 * 2
                                                   + (size_t)ACC_N * 4);

    fm_prep<<<dim3(SBLK + PACKBLK), dim3(256), 0, stream>>>(x, emb_w, bias_w,
                                                            bm2, embB, cB2c, acc);
    fm_main<<<dim3(ROWBLK, NCHUNK), dim3(512), 0, stream>>>(bm2, embB, cB2c, acc);
    fm_final<<<dim3((B_ROWS + 255) / 256), dim3(256), 0, stream>>>(acc, g_bias, out);
}

// Round 5
// 819.503 us; speedup vs baseline: 1.1187x; 1.0931x over previous
//
#include <hip/hip_runtime.h>
#include <hip/hip_bf16.h>

#define B_ROWS 1024
#define F_FLD  160000
#define D_DIM  16
#define NKB    (F_FLD / 32)        // 5000 K-blocks of 32 cols
#define NSTAT  (D_DIM + 1)         // 16 ev + cacc
#define ACC_N  (B_ROWS * NSTAT)    // 17408
#define CCOLS  6400                // cols per block chunk
#define NGRP   (CCOLS / 256)       // 25 ballot groups per chunk
#define KBC    (CCOLS / 32)        // 200 K-blocks per chunk
#define NCHUNK (F_FLD / CCOLS)     // 25
#define ROWS_B 32                  // rows per block
#define ROWBLK (B_ROWS / ROWS_B)   // 32 row-blocks
#define WAVES  8                   // 512 threads

typedef __attribute__((ext_vector_type(8))) short bf16x8;
typedef __attribute__((ext_vector_type(4))) float f32x4;
typedef __attribute__((ext_vector_type(4))) int   i32x4;   // native vec for nontemporal builtin

static __device__ inline unsigned short f2bf(float x) {
    __hip_bfloat16 h = __float2bfloat16(x);
    union { __hip_bfloat16 h; unsigned short s; } u; u.h = h; return u.s;
}

// Expand 8 mask bits -> 8 bf16 (1.0/0.0) in A-fragment register order.
// (verbatim from R4/R5, passing with absmax = bf16 noise)
static __device__ inline bf16x8 expand8(unsigned b) {
    union { unsigned u[4]; bf16x8 v; } r;
    r.u[0] = ((b        & 1u) * 0x3F80u) | (((b >> 1) & 1u) * 0x3F800000u);
    r.u[1] = (((b >> 2) & 1u) * 0x3F80u) | (((b >> 3) & 1u) * 0x3F800000u);
    r.u[2] = (((b >> 4) & 1u) * 0x3F80u) | (((b >> 5) & 1u) * 0x3F800000u);
    r.u[3] = (((b >> 6) & 1u) * 0x3F80u) | (((b >> 7) & 1u) * 0x3F800000u);
    return r.v;
}

// Pack emb -> B-frag bf16 (embB[kb][lane][j] = emb[kb*32+4j+q][n], q=lane>>4,
// n=lane&15) and c -> broadcast-B (cB2c[kb][q][j] = bias[f]-0.5||emb[f]||^2,
// f=kb*32+4j+q), computing the row norms in-register via 16-lane butterfly.
// Also zeroes acc (ws is poisoned 0xAA every call).
__global__ __launch_bounds__(256) void fm_pack(const float* __restrict__ emb,
                                               const float* __restrict__ bias,
                                               unsigned short* __restrict__ embB,
                                               unsigned short* __restrict__ cB2c,
                                               float* __restrict__ acc) {
    const int tid = threadIdx.x;
    const int kb = blockIdx.x * 4 + (tid >> 6);
    const int l = tid & 63, q = l >> 4, n = l & 15;

    float e[8];
    union { unsigned short s[8]; uint4 u; } v;
#pragma unroll
    for (int j = 0; j < 8; ++j) {
        int f = kb * 32 + 4 * j + q;
        e[j] = emb[(size_t)f * D_DIM + n];
        v.s[j] = f2bf(e[j]);
    }
    *(uint4*)(embB + ((size_t)kb * 64 + l) * 8) = v.u;

    union { unsigned short s[8]; uint4 u; } w;
#pragma unroll
    for (int j = 0; j < 8; ++j) {
        float s = e[j] * e[j];                    // reduce over n (16 lanes)
        s += __shfl_xor(s, 1);
        s += __shfl_xor(s, 2);
        s += __shfl_xor(s, 4);
        s += __shfl_xor(s, 8);
        int f = kb * 32 + 4 * j + q;
        w.s[j] = f2bf((n == 0 ? bias[f] : 0.0f) - 0.5f * s);
    }
    if (n == 0) *(uint4*)(cB2c + ((size_t)kb * 4 + q) * 8) = w.u;

    int gid = blockIdx.x * 256 + tid;
    if (gid < ACC_N) acc[gid] = 0.0f;
}

// Main: R10 = R6 fused structure (best measured, 851 us total) with ONE change:
// the x stage loads are NONTEMPORAL (via native ext_vector i32x4 pointer —
// the HIP_vector_type int4 is rejected by the builtin). R8 proved the
// ~3.05 TB/s x-read rate is shape-independent (copy-shaped full-occupancy
// reader = chunked stage = long streams, all ~3 TB/s, while pure WRITE hits
// 6.3) -> hypothesis: the read-fill/allocation path through L2+L3 (655 MB
// sweeping a 256 MB L3, 100% miss + evict) is the limiter, not DRAM pins.
// nt loads skip/deprioritize allocation.
// Prediction: stage rate 3.05 -> >=5 TB/s, fm_main 215 -> ~125-150 us.
// If neutral: ~3.1 TB/s is the device read ceiling and R6 was at roofline.
__global__ __launch_bounds__(512, 6) void fm_main(const int* __restrict__ x,
                                                  const unsigned short* __restrict__ embB,
                                                  const unsigned short* __restrict__ cB2c,
                                                  float* __restrict__ acc) {
    __shared__ unsigned long long msk[NGRP][ROWS_B][4];   // 25.6 KB
    __shared__ float red[WAVES][ROWS_B][NSTAT];           // 17.4 KB

    const int tid = threadIdx.x;
    const int w = tid >> 6, l = tid & 63;
    const int q = l >> 4, n = l & 15;
    const int rowbase = blockIdx.x * ROWS_B;   // rowblock = fastest grid dim
    const int c0 = blockIdx.y * CCOLS;         // chunk    = slow grid dim

    // ---- stage: wave w -> rows 4w..4w+3; each row read as one sequential
    // 25.6 KB stream (bit l of word j_w at group g <-> col g*256 + 4l + j_w)
#pragma unroll
    for (int rr = 0; rr < 4; ++rr) {
        const int rloc = 4 * w + rr;
        const i32x4* xp = (const i32x4*)(x + (size_t)(rowbase + rloc) * F_FLD + c0) + l;
        for (int g0 = 0; g0 < NGRP; g0 += 5) {
            i32x4 v[5];
#pragma unroll
            for (int k = 0; k < 5; ++k)
                v[k] = __builtin_nontemporal_load(xp + (size_t)(g0 + k) * 64);
#pragma unroll
            for (int k = 0; k < 5; ++k) {
                unsigned long long m0 = __ballot(v[k].x > 0);
                unsigned long long m1 = __ballot(v[k].y > 0);
                unsigned long long m2 = __ballot(v[k].z > 0);
                unsigned long long m3 = __ballot(v[k].w > 0);
                if (l == 0) {
                    msk[g0 + k][rloc][0] = m0; msk[g0 + k][rloc][1] = m1;
                    msk[g0 + k][rloc][2] = m2; msk[g0 + k][rloc][3] = m3;
                }
            }
        }
    }
    __syncthreads();

    // ---- compute: wave w owns K-blocks w*25 .. w*25+24; one eB load feeds
    // both row-halves (rows 0-15 via A0, rows 16-31 via A1).
    f32x4 aev0 = {0.f, 0.f, 0.f, 0.f}, ac0 = {0.f, 0.f, 0.f, 0.f};
    f32x4 aev1 = {0.f, 0.f, 0.f, 0.f}, ac1 = {0.f, 0.f, 0.f, 0.f};
    const uint4* eB = (const uint4*)embB;
    const uint4* cB = (const uint4*)cB2c;
    const int kbg0 = blockIdx.y * KBC;

#pragma unroll 2
    for (int t = 0; t < KBC / WAVES; ++t) {
        const int kb = w * (KBC / WAVES) + t;        // 0..199 within chunk
        const int g = kb >> 3, byt = kb & 7;
        // A byte: bits j of byte `byt` of word q, row n  (verified mapping:
        // col kb*32 + 4j + q  ==  bit (byt*8+j) of word q at group g)
        unsigned long long mv0 = msk[g][n][q];
        unsigned long long mv1 = msk[g][n + 16][q];
        unsigned b0 = (unsigned)(mv0 >> (8 * byt)) & 0xFFu;
        unsigned b1 = (unsigned)(mv1 >> (8 * byt)) & 0xFFu;
        bf16x8 A0 = expand8(b0);
        bf16x8 A1 = expand8(b1);
        union { uint4 u; bf16x8 v; } Bf, Cf;
        Bf.u = eB[(size_t)(kbg0 + kb) * 64 + l];
        Cf.u = cB[(size_t)(kbg0 + kb) * 4 + q];
        aev0 = __builtin_amdgcn_mfma_f32_16x16x32_bf16(A0, Bf.v, aev0, 0, 0, 0);
        ac0  = __builtin_amdgcn_mfma_f32_16x16x32_bf16(A0, Cf.v, ac0,  0, 0, 0);
        aev1 = __builtin_amdgcn_mfma_f32_16x16x32_bf16(A1, Bf.v, aev1, 0, 0, 0);
        ac1  = __builtin_amdgcn_mfma_f32_16x16x32_bf16(A1, Cf.v, ac1,  0, 0, 0);
    }

    // ---- reduce 8 wave-partials (C/D layout: row = q*4+r, col = n;
    // A1's outputs land on block rows 16 + q*4+r)
#pragma unroll
    for (int r = 0; r < 4; ++r) {
        red[w][q * 4 + r][n] = aev0[r];
        red[w][16 + q * 4 + r][n] = aev1[r];
        if (n == 0) {
            red[w][q * 4 + r][16] = ac0[r];
            red[w][16 + q * 4 + r][16] = ac1[r];
        }
    }
    __syncthreads();

    for (int i = tid; i < ROWS_B * NSTAT; i += 512) {
        int row = i / NSTAT, col = i % NSTAT;
        float s = 0.0f;
#pragma unroll
        for (int ww = 0; ww < WAVES; ++ww) s += red[ww][row][col];
        atomicAdd(acc + (size_t)(rowbase + row) * NSTAT + col, s);
    }
}

// out[b] = g_bias + cacc[b] + 0.5 * ||ev[b]||^2
__global__ __launch_bounds__(256) void fm_final(const float* __restrict__ acc,
                                                const float* __restrict__ g_bias,
                                                float* __restrict__ out) {
    int row = blockIdx.x * 256 + threadIdx.x;
    if (row >= B_ROWS) return;
    const float* a = acc + (size_t)row * NSTAT;
    float s = 0.0f;
#pragma unroll
    for (int d = 0; d < D_DIM; ++d) s += a[d] * a[d];
    out[row] = g_bias[0] + a[16] + 0.5f * s;
}

extern "C" void kernel_launch(void* const* d_in, const int* in_sizes, int n_in,
                              void* d_out, int out_size, void* d_ws, size_t ws_size,
                              hipStream_t stream) {
    const int*   x      = (const int*)d_in[0];
    const float* emb_w  = (const float*)d_in[1];
    const float* bias_w = (const float*)d_in[2];
    const float* g_bias = (const float*)d_in[3];
    float*       out    = (float*)d_out;

    // ws: embB 5,120,000 | cB2c 320,000 | acc 69,632
    unsigned short* embB = (unsigned short*)d_ws;
    unsigned short* cB2c = (unsigned short*)((char*)d_ws + (size_t)NKB * 64 * 8 * 2);
    float*          acc  = (float*)((char*)d_ws + (size_t)NKB * 64 * 8 * 2
                                                + (size_t)NKB * 4 * 8 * 2);

    fm_pack<<<dim3(NKB / 4), dim3(256), 0, stream>>>(emb_w, bias_w, embB, cB2c, acc);
    fm_main<<<dim3(ROWBLK, NCHUNK), dim3(512), 0, stream>>>(x, embB, cB2c, acc);
    fm_final<<<dim3((B_ROWS + 255) / 256), dim3(256), 0, stream>>>(acc, g_bias, out);
}

// Round 6
// 818.543 us; speedup vs baseline: 1.1200x; 1.0012x over previous
//
#include <hip/hip_runtime.h>
#include <hip/hip_bf16.h>

#define B_ROWS 1024
#define F_FLD  160000
#define D_DIM  16
#define NKB    (F_FLD / 32)        // 5000 K-blocks of 32 cols
#define NSTAT  (D_DIM + 1)         // 16 ev + cacc
#define ACC_N  (B_ROWS * NSTAT)    // 17408
#define CCOLS  6400                // cols per block chunk
#define NGRP   (CCOLS / 256)       // 25 ballot groups per chunk
#define KBC    (CCOLS / 32)        // 200 K-blocks per chunk
#define NCHUNK (F_FLD / CCOLS)     // 25
#define ROWS_B 32                  // rows per block
#define ROWBLK (B_ROWS / ROWS_B)   // 32 row-blocks
#define WAVES  8                   // 512 threads

typedef __attribute__((ext_vector_type(8))) short bf16x8;
typedef __attribute__((ext_vector_type(4))) float f32x4;
typedef __attribute__((ext_vector_type(4))) int   i32x4;   // native vec for nontemporal builtin

static __device__ inline unsigned short f2bf(float x) {
    __hip_bfloat16 h = __float2bfloat16(x);
    union { __hip_bfloat16 h; unsigned short s; } u; u.h = h; return u.s;
}

// Expand 8 mask bits -> 8 bf16 (1.0/0.0) in A-fragment register order.
// (verbatim from R4/R5, passing with absmax = bf16 noise)
static __device__ inline bf16x8 expand8(unsigned b) {
    union { unsigned u[4]; bf16x8 v; } r;
    r.u[0] = ((b        & 1u) * 0x3F80u) | (((b >> 1) & 1u) * 0x3F800000u);
    r.u[1] = (((b >> 2) & 1u) * 0x3F80u) | (((b >> 3) & 1u) * 0x3F800000u);
    r.u[2] = (((b >> 4) & 1u) * 0x3F80u) | (((b >> 5) & 1u) * 0x3F800000u);
    r.u[3] = (((b >> 6) & 1u) * 0x3F80u) | (((b >> 7) & 1u) * 0x3F800000u);
    return r.v;
}

// Pack emb -> B-frag bf16 (embB[kb][lane][j] = emb[kb*32+4j+q][n], q=lane>>4,
// n=lane&15) and c -> broadcast-B (cB2c[kb][q][j] = bias[f]-0.5||emb[f]||^2,
// f=kb*32+4j+q), computing the row norms in-register via 16-lane butterfly.
// Also zeroes acc (ws is poisoned 0xAA every call).
__global__ __launch_bounds__(256) void fm_pack(const float* __restrict__ emb,
                                               const float* __restrict__ bias,
                                               unsigned short* __restrict__ embB,
                                               unsigned short* __restrict__ cB2c,
                                               float* __restrict__ acc) {
    const int tid = threadIdx.x;
    const int kb = blockIdx.x * 4 + (tid >> 6);
    const int l = tid & 63, q = l >> 4, n = l & 15;

    float e[8];
    union { unsigned short s[8]; uint4 u; } v;
#pragma unroll
    for (int j = 0; j < 8; ++j) {
        int f = kb * 32 + 4 * j + q;
        e[j] = emb[(size_t)f * D_DIM + n];
        v.s[j] = f2bf(e[j]);
    }
    *(uint4*)(embB + ((size_t)kb * 64 + l) * 8) = v.u;

    union { unsigned short s[8]; uint4 u; } w;
#pragma unroll
    for (int j = 0; j < 8; ++j) {
        float s = e[j] * e[j];                    // reduce over n (16 lanes)
        s += __shfl_xor(s, 1);
        s += __shfl_xor(s, 2);
        s += __shfl_xor(s, 4);
        s += __shfl_xor(s, 8);
        int f = kb * 32 + 4 * j + q;
        w.s[j] = f2bf((n == 0 ? bias[f] : 0.0f) - 0.5f * s);
    }
    if (n == 0) *(uint4*)(cB2c + ((size_t)kb * 4 + q) * 8) = w.u;

    int gid = blockIdx.x * 256 + tid;
    if (gid < ACC_N) acc[gid] = 0.0f;
}

// Main: R11 = R10 (nt loads, best measured 819.5 us) with ONE change: the
// stage loop ping-pongs two 5-load nt batches so ballots of batch A overlap
// batch B's in-flight loads (the wave never drains vmcnt to 0). Rationale:
// nt bypasses cache allocation -> every load pays full DRAM latency; R10's
// drain-per-batch leaves a latency bubble per 5 KB. R8 proved depth was
// irrelevant WITHOUT nt; with nt the latency term is 3-4x larger.
// Prediction: stage 3.6 -> 4.2+ TB/s (total -> ~790-800); if neutral, the
// read path is saturated and R10/R11 is at roofline.
__global__ __launch_bounds__(512, 6) void fm_main(const int* __restrict__ x,
                                                  const unsigned short* __restrict__ embB,
                                                  const unsigned short* __restrict__ cB2c,
                                                  float* __restrict__ acc) {
    __shared__ unsigned long long msk[NGRP][ROWS_B][4];   // 25.6 KB
    __shared__ float red[WAVES][ROWS_B][NSTAT];           // 17.4 KB

    const int tid = threadIdx.x;
    const int w = tid >> 6, l = tid & 63;
    const int q = l >> 4, n = l & 15;
    const int rowbase = blockIdx.x * ROWS_B;   // rowblock = fastest grid dim
    const int c0 = blockIdx.y * CCOLS;         // chunk    = slow grid dim

    // ---- stage: wave w -> rows 4w..4w+3; each row read as one sequential
    // 25.6 KB stream (bit l of word j_w at group g <-> col g*256 + 4l + j_w)
#pragma unroll
    for (int rr = 0; rr < 4; ++rr) {
        const int rloc = 4 * w + rr;
        const i32x4* xp = (const i32x4*)(x + (size_t)(rowbase + rloc) * F_FLD + c0) + l;

        i32x4 va[5], vb[5];
        auto LD = [&](i32x4 (&r)[5], int g0) {
#pragma unroll
            for (int k = 0; k < 5; ++k)
                r[k] = __builtin_nontemporal_load(xp + (size_t)(g0 + k) * 64);
        };
        auto BAL = [&](i32x4 (&r)[5], int g0) {
#pragma unroll
            for (int k = 0; k < 5; ++k) {
                unsigned long long m0 = __ballot(r[k].x > 0);
                unsigned long long m1 = __ballot(r[k].y > 0);
                unsigned long long m2 = __ballot(r[k].z > 0);
                unsigned long long m3 = __ballot(r[k].w > 0);
                if (l == 0) {
                    msk[g0 + k][rloc][0] = m0; msk[g0 + k][rloc][1] = m1;
                    msk[g0 + k][rloc][2] = m2; msk[g0 + k][rloc][3] = m3;
                }
            }
        };

        LD(va, 0);
#pragma unroll 1
        for (int g0 = 0; g0 < NGRP; g0 += 10) {
            const bool hasB = (g0 + 5) < NGRP;
            if (hasB) LD(vb, g0 + 5);
            BAL(va, g0);
            if (g0 + 10 < NGRP) LD(va, g0 + 10);
            if (hasB) BAL(vb, g0 + 5);
        }
    }
    __syncthreads();

    // ---- compute: wave w owns K-blocks w*25 .. w*25+24; one eB load feeds
    // both row-halves (rows 0-15 via A0, rows 16-31 via A1).
    f32x4 aev0 = {0.f, 0.f, 0.f, 0.f}, ac0 = {0.f, 0.f, 0.f, 0.f};
    f32x4 aev1 = {0.f, 0.f, 0.f, 0.f}, ac1 = {0.f, 0.f, 0.f, 0.f};
    const uint4* eB = (const uint4*)embB;
    const uint4* cB = (const uint4*)cB2c;
    const int kbg0 = blockIdx.y * KBC;

#pragma unroll 2
    for (int t = 0; t < KBC / WAVES; ++t) {
        const int kb = w * (KBC / WAVES) + t;        // 0..199 within chunk
        const int g = kb >> 3, byt = kb & 7;
        // A byte: bits j of byte `byt` of word q, row n  (verified mapping:
        // col kb*32 + 4j + q  ==  bit (byt*8+j) of word q at group g)
        unsigned long long mv0 = msk[g][n][q];
        unsigned long long mv1 = msk[g][n + 16][q];
        unsigned b0 = (unsigned)(mv0 >> (8 * byt)) & 0xFFu;
        unsigned b1 = (unsigned)(mv1 >> (8 * byt)) & 0xFFu;
        bf16x8 A0 = expand8(b0);
        bf16x8 A1 = expand8(b1);
        union { uint4 u; bf16x8 v; } Bf, Cf;
        Bf.u = eB[(size_t)(kbg0 + kb) * 64 + l];
        Cf.u = cB[(size_t)(kbg0 + kb) * 4 + q];
        aev0 = __builtin_amdgcn_mfma_f32_16x16x32_bf16(A0, Bf.v, aev0, 0, 0, 0);
        ac0  = __builtin_amdgcn_mfma_f32_16x16x32_bf16(A0, Cf.v, ac0,  0, 0, 0);
        aev1 = __builtin_amdgcn_mfma_f32_16x16x32_bf16(A1, Bf.v, aev1, 0, 0, 0);
        ac1  = __builtin_amdgcn_mfma_f32_16x16x32_bf16(A1, Cf.v, ac1,  0, 0, 0);
    }

    // ---- reduce 8 wave-partials (C/D layout: row = q*4+r, col = n;
    // A1's outputs land on block rows 16 + q*4+r)
#pragma unroll
    for (int r = 0; r < 4; ++r) {
        red[w][q * 4 + r][n] = aev0[r];
        red[w][16 + q * 4 + r][n] = aev1[r];
        if (n == 0) {
            red[w][q * 4 + r][16] = ac0[r];
            red[w][16 + q * 4 + r][16] = ac1[r];
        }
    }
    __syncthreads();

    for (int i = tid; i < ROWS_B * NSTAT; i += 512) {
        int row = i / NSTAT, col = i % NSTAT;
        float s = 0.0f;
#pragma unroll
        for (int ww = 0; ww < WAVES; ++ww) s += red[ww][row][col];
        atomicAdd(acc + (size_t)(rowbase + row) * NSTAT + col, s);
    }
}

// out[b] = g_bias + cacc[b] + 0.5 * ||ev[b]||^2
__global__ __launch_bounds__(256) void fm_final(const float* __restrict__ acc,
                                                const float* __restrict__ g_bias,
                                                float* __restrict__ out) {
    int row = blockIdx.x * 256 + threadIdx.x;
    if (row >= B_ROWS) return;
    const float* a = acc + (size_t)row * NSTAT;
    float s = 0.0f;
#pragma unroll
    for (int d = 0; d < D_DIM; ++d) s += a[d] * a[d];
    out[row] = g_bias[0] + a[16] + 0.5f * s;
}

extern "C" void kernel_launch(void* const* d_in, const int* in_sizes, int n_in,
                              void* d_out, int out_size, void* d_ws, size_t ws_size,
                              hipStream_t stream) {
    const int*   x      = (const int*)d_in[0];
    const float* emb_w  = (const float*)d_in[1];
    const float* bias_w = (const float*)d_in[2];
    const float* g_bias = (const float*)d_in[3];
    float*       out    = (float*)d_out;

    // ws: embB 5,120,000 | cB2c 320,000 | acc 69,632
    unsigned short* embB = (unsigned short*)d_ws;
    unsigned short* cB2c = (unsigned short*)((char*)d_ws + (size_t)NKB * 64 * 8 * 2);
    float*          acc  = (float*)((char*)d_ws + (size_t)NKB * 64 * 8 * 2
                                                + (size_t)NKB * 4 * 8 * 2);

    fm_pack<<<dim3(NKB / 4), dim3(256), 0, stream>>>(emb_w, bias_w, embB, cB2c, acc);
    fm_main<<<dim3(ROWBLK, NCHUNK), dim3(512), 0, stream>>>(x, embB, cB2c, acc);
    fm_final<<<dim3((B_ROWS + 255) / 256), dim3(256), 0, stream>>>(acc, g_bias, out);
}